// Round 14
// baseline (986.824 us; speedup 1.0000x reference)
//
#include <hip/hip_runtime.h>
#include <hip/hip_bf16.h>

typedef __bf16 bf16x8 __attribute__((ext_vector_type(8)));
typedef float f32x4 __attribute__((ext_vector_type(4)));
typedef int i32x4 __attribute__((ext_vector_type(4)));

#define NB 32
#define NS 200
#define SP 256
#define ND 256
#define NH 6
#define NL 8
#define NBS (NB*NS)      // 6400
#define NZ (NB*NH)       // 192
#define SLAB (SP*ND)     // 65536
#define PSTR 264         // P lds row stride (shorts)

using bf16 = __hip_bfloat16;

enum { EPI_F32 = 0, EPI_RELU_BF = 1 };

__device__ __forceinline__ float b2f(bf16 x) { return __bfloat162float(x); }
__device__ __forceinline__ bf16 f2b(float x) { return __float2bfloat16(x); }
__device__ __forceinline__ unsigned short fbits(float x) { bf16 h = f2b(x); return *(unsigned short*)&h; }

#define MFMA __builtin_amdgcn_mfma_f32_16x16x32_bf16

// async global->LDS, 16B per lane. LDS dest must be wave-uniform base (HW adds lane*16).
__device__ __forceinline__ void gload16(const bf16* g, const short* l) {
    __builtin_amdgcn_global_load_lds(
        (const __attribute__((address_space(1))) unsigned int*)(unsigned long long)(g),
        (__attribute__((address_space(3))) unsigned int*)(unsigned long long)(l), 16, 0, 0);
}

// LDS swizzle: rows are 64B = 4 x 16B units; XOR unit with (row>>1)&3 -> 2-way/bank (free).
// gload_lds dest is linear, so apply the permutation on the per-lane GLOBAL source (m173).
#define GUNIT(lane) ((((lane) & 3) ^ (((lane) >> 3) & 3)) * 8)
#define RUNIT(kcu, fr) ((((kcu) ^ (((fr) >> 1) & 3))) * 8)

// ---------------------------------------------------------------------------
// QKV GEMM v2: block = 64 dims x 256 tokens (4 n-tiles). Phase A: full A-tile
// (64x256) staged once to LDS, A-fragments lifted to 64 VGPRs, LDS released.
// Phase B: seamless 32-step pipeline (4 n-tiles x 8 k-steps), B-only staging
// (4KB/step for 4 MFMA -- half the bytes/MFMA of the r13 kernel), 4 bufs,
// single barrier/step, counted vmcnt(2/1/0). Per-tile epilogue: Q/K via LDS
// transpose in a disjoint region -> 128B-coalesced stores; V direct (32B segs).
// ---------------------------------------------------------------------------
__global__ __launch_bounds__(256)
void gemm_qkv(const bf16* __restrict__ A, const bf16* __restrict__ Bm,
              const float* __restrict__ qkvb, const float* __restrict__ tnbp,
              bf16* __restrict__ Qb, bf16* __restrict__ Kb, bf16* __restrict__ Vb)
{
    __shared__ __align__(16) char smem[32768];
    short* Asl = (short*)smem;                  // phase A: 8 chunks x [64][32] = 32KB
    short* Bsl = (short*)smem;                  // phase B: 4 bufs x [64][32] = 16KB
    short* T   = (short*)(smem + 16384);        // 64x72 shorts = 9KB (disjoint from Bsl)
    const int K = 256;
    const int tid  = threadIdx.x;
    const int m0   = blockIdx.y * 64;
    const int n0   = blockIdx.x * 256;
    const int lane = tid & 63, w = tid >> 6;
    const int wm   = (w >> 1) * 32, wn = (w & 1) * 32;
    const int fr   = lane & 15, kcu = lane >> 4;
    const int srow = lane >> 2, schk = GUNIT(lane);

    const bf16* Ag = A + (long long)m0 * K;

    // ---- phase A: stage A-tile, lift fragments to registers ----
#pragma unroll
    for (int c = 0; c < 8; c++)
        gload16(Ag + (long long)(w*16 + srow)*K + c*32 + schk, &Asl[c*2048 + (w*16)*32]);
    asm volatile("s_waitcnt vmcnt(0)" ::: "memory");
    __builtin_amdgcn_s_barrier();
    __builtin_amdgcn_sched_barrier(0);
    bf16x8 afr[2][8];
#pragma unroll
    for (int c = 0; c < 8; c++)
#pragma unroll
        for (int i = 0; i < 2; i++)
            afr[i][c] = *(const bf16x8*)&Asl[c*2048 + (wm + i*16 + fr)*32 + RUNIT(kcu, fr)];
    asm volatile("s_waitcnt lgkmcnt(0)" ::: "memory");
    __builtin_amdgcn_sched_barrier(0);
    __builtin_amdgcn_s_barrier();               // all A-reads done before B DMA overwrites
    __builtin_amdgcn_sched_barrier(0);

    // ---- phase B: 32-step pipeline over (nt4, t) ----
    const int xq   = m0 / 1536;                 // uniform per block
    const int c1_0 = m0 - xq*1536;
    const int hdq  = c1_0 >> 8;
    const int ddb  = c1_0 & 255;

    auto stageB = [&](int g) {                  // g = global step index
        const int nt4 = g >> 3, ts = g & 7, buf = g & 3;
        gload16(Bm + (long long)(n0 + nt4*64 + w*16 + srow)*K + ts*32 + schk,
                &Bsl[buf*2048 + (w*16)*32]);
    };

    f32x4 acc[2][2];
#pragma unroll
    for (int i = 0; i < 2; i++)
#pragma unroll
        for (int j = 0; j < 2; j++) acc[i][j] = (f32x4){0.f,0.f,0.f,0.f};

    stageB(0);
    stageB(1);
    for (int nt4 = 0; nt4 < 4; nt4++) {
#pragma unroll
        for (int t = 0; t < 8; t++) {
            const int g = nt4*8 + t;
            const int buf = g & 3;
            if (g + 2 < 32) {
                stageB(g + 2);
                asm volatile("s_waitcnt vmcnt(2)" ::: "memory");   // step-g B landed
            } else if (g + 1 < 32) {
                asm volatile("s_waitcnt vmcnt(1)" ::: "memory");
            } else {
                asm volatile("s_waitcnt vmcnt(0)" ::: "memory");
            }
            __builtin_amdgcn_s_barrier();
            __builtin_amdgcn_sched_barrier(0);
            bf16x8 b0 = *(const bf16x8*)&Bsl[buf*2048 + (wn      + fr)*32 + RUNIT(kcu, fr)];
            bf16x8 b1 = *(const bf16x8*)&Bsl[buf*2048 + (wn + 16 + fr)*32 + RUNIT(kcu, fr)];
            acc[0][0] = MFMA(afr[0][t], b0, acc[0][0], 0, 0, 0);
            acc[0][1] = MFMA(afr[0][t], b1, acc[0][1], 0, 0, 0);
            acc[1][0] = MFMA(afr[1][t], b0, acc[1][0], 0, 0, 0);
            acc[1][1] = MFMA(afr[1][t], b1, acc[1][1], 0, 0, 0);
            // single barrier/step: 4-buf D=2 => stage target never collides
        }

        // ---- epilogue for n-tile nt4 ----
        const int nb = n0 + nt4*64;
        if (xq < 2) {
            __syncthreads();                    // prior T readers done
#pragma unroll
            for (int i = 0; i < 2; i++) {
                const int dl0 = wm + i*16 + kcu*4;
                float bv[4];
#pragma unroll
                for (int rg = 0; rg < 4; rg++) {
                    const int cc = c1_0 + dl0 + rg;
                    bv[rg] = (cc < 512) ? qkvb[xq*512 + cc] : tnbp[xq*1024 + cc - 512];
                }
#pragma unroll
                for (int j = 0; j < 2; j++) {
                    const int tok = wn + j*16 + fr;
                    ushort4 pk;
                    pk.x = fbits(acc[i][j][0] + bv[0]);
                    pk.y = fbits(acc[i][j][1] + bv[1]);
                    pk.z = fbits(acc[i][j][2] + bv[2]);
                    pk.w = fbits(acc[i][j][3] + bv[3]);
                    *(ushort4*)&T[tok*72 + dl0] = pk;
                }
            }
            __syncthreads();
            const int tt = tid >> 2;            // local token
            const int dc = (tid & 3) * 16;      // 32B dim chunk
            const int c  = nb + tt;
            const int bb = c / NS, ss = c - bb*NS;
            bf16* dst = xq ? Kb : Qb;
            bf16* dp  = dst + ((long long)((bb*NH + hdq)*SP + ss))*ND + ddb + dc;
            *(i32x4*)dp       = *(const i32x4*)&T[tt*72 + dc];
            *(i32x4*)(dp + 8) = *(const i32x4*)&T[tt*72 + dc + 8];
        } else {
#pragma unroll
            for (int i = 0; i < 2; i++) {
                const int dl0 = wm + i*16 + kcu*4;
                float bv[4];
#pragma unroll
                for (int rg = 0; rg < 4; rg++) {
                    const int cc = c1_0 + dl0 + rg;
                    bv[rg] = (cc < 512) ? qkvb[2*512 + cc] : tnbp[2*1024 + cc - 512];
                }
#pragma unroll
                for (int j = 0; j < 2; j++) {
                    const int c = nb + wn + j*16 + fr;
                    const int bb = c / NS, ss = c - bb*NS;
                    const long long base = ((long long)((bb*NH + hdq)*ND + ddb + dl0))*SP + ss;
#pragma unroll
                    for (int rg = 0; rg < 4; rg++)
                        Vb[base + (long long)rg*SP] = f2b(acc[i][j][rg] + bv[rg]);
                }
            }
        }
#pragma unroll
        for (int i = 0; i < 2; i++)
#pragma unroll
            for (int j = 0; j < 2; j++) acc[i][j] = (f32x4){0.f,0.f,0.f,0.f};
    }
}

// ---------------------------------------------------------------------------
// NT GEMM 128x128 for outproj / ff1 / ff2 (r11-proven).
// 3 LDS bufs, D=1, ONE barrier/iter. blockIdx.z = split-K chunk.
// ---------------------------------------------------------------------------
template<int MODE>
__global__ __launch_bounds__(256)
void gemm_nt(const bf16* __restrict__ A, const bf16* __restrict__ Bm,
             int M, int N, int K, int Kspan, long long sOz,
             float* __restrict__ outF, bf16* __restrict__ outBf,
             const float* __restrict__ bias)
{
    __shared__ short Asl[3][128*32];
    __shared__ short Bsl[3][128*32];
    const int tid  = threadIdx.x;
    const int m0   = blockIdx.y * 128;
    const int n0   = blockIdx.x * 128;
    const int kbase= blockIdx.z * Kspan;
    const int lane = tid & 63, w = tid >> 6;
    const int wm   = (w >> 1) * 64, wn = (w & 1) * 64;
    const int fr   = lane & 15, kc = (lane >> 4) * 8;
    const int srow = lane >> 2, schk = (lane & 3) * 8;

    const bf16* Ag = A  + (long long)m0 * K + kbase;
    const bf16* Bg = Bm + (long long)n0 * K + kbase;

    f32x4 acc[4][4];
#pragma unroll
    for (int i = 0; i < 4; i++)
#pragma unroll
        for (int j = 0; j < 4; j++) acc[i][j] = (f32x4){0.f,0.f,0.f,0.f};

    auto stage = [&](int buf, int k0) {
        gload16(Ag + (long long)(w*32      + srow)*K + k0 + schk, &Asl[buf][(w*32     )*32]);
        gload16(Ag + (long long)(w*32 + 16 + srow)*K + k0 + schk, &Asl[buf][(w*32 + 16)*32]);
        gload16(Bg + (long long)(w*32      + srow)*K + k0 + schk, &Bsl[buf][(w*32     )*32]);
        gload16(Bg + (long long)(w*32 + 16 + srow)*K + k0 + schk, &Bsl[buf][(w*32 + 16)*32]);
    };

    const int nt = Kspan >> 5;
    stage(0, 0);
    for (int t = 0; t < nt; t++) {
        const int buf = t % 3;
        if (t + 1 < nt) {
            stage((t + 1) % 3, (t + 1) * 32);
            asm volatile("s_waitcnt vmcnt(4)" ::: "memory");
        } else {
            asm volatile("s_waitcnt vmcnt(0)" ::: "memory");
        }
        __builtin_amdgcn_s_barrier();
        __builtin_amdgcn_sched_barrier(0);
        bf16x8 af[4], bfm[4];
#pragma unroll
        for (int i = 0; i < 4; i++) af[i]  = *(const bf16x8*)&Asl[buf][(wm + i*16 + fr)*32 + kc];
#pragma unroll
        for (int j = 0; j < 4; j++) bfm[j] = *(const bf16x8*)&Bsl[buf][(wn + j*16 + fr)*32 + kc];
#pragma unroll
        for (int i = 0; i < 4; i++)
#pragma unroll
            for (int j = 0; j < 4; j++)
                acc[i][j] = MFMA(af[i], bfm[j], acc[i][j], 0, 0, 0);
    }

    const int rq = (lane >> 4) * 4;
#pragma unroll
    for (int i = 0; i < 4; i++) {
        const int r0 = m0 + wm + i*16 + rq;
#pragma unroll
        for (int j = 0; j < 4; j++) {
            const int c = n0 + wn + j*16 + fr;
            if (MODE == EPI_F32) {
#pragma unroll
                for (int rg = 0; rg < 4; rg++)
                    outF[(long long)blockIdx.z * sOz + (long long)(r0+rg)*N + c] = acc[i][j][rg];
            } else {
                const float bv = bias[c];
#pragma unroll
                for (int rg = 0; rg < 4; rg++)
                    outBf[(long long)(r0+rg)*N + c] = f2b(fmaxf(acc[i][j][rg] + bv, 0.f));
            }
        }
    }
}

// ---------------------------------------------------------------------------
// Fused attention (r11-proven): block = (z, 64-query quarter); grid (192, 4).
// ---------------------------------------------------------------------------
__global__ __launch_bounds__(256)
void attn_fused(const bf16* __restrict__ Qb, const bf16* __restrict__ Kb,
                const bf16* __restrict__ Vtb, const int* __restrict__ tokens,
                bf16* __restrict__ ctx)
{
    __shared__ __align__(16) char smem[2*20480 + 1024 + 1024 + 64*PSTR*2];
    float* red   = (float*)(smem + 40960);
    float* maskv = (float*)(smem + 40960 + 1024);
    short* P     = (short*)(smem + 40960 + 2048);

    const int z  = blockIdx.x;
    const int b  = z / NH, h = z - b*NH;
    const int q0 = blockIdx.y * 64;
    const int tid = threadIdx.x;
    const int lane = tid & 63, w = tid >> 6;
    const int fr = lane & 15, qh = lane >> 4;
    const int kc = qh * 8;
    const int srow = lane >> 2, schk = GUNIT(lane);

    const bf16* Kp = Kb  + (long long)z * SLAB;
    const bf16* Qp = Qb  + (long long)z * SLAB;
    const bf16* Vp = Vtb + (long long)z * SLAB;

    {
        const int s = tid;
        float mv = -1e9f;
        if (s < NS && tokens[b*NS + s] != 0) mv = 0.f;
        maskv[s] = mv;
    }

    auto stage1 = [&](int buf, int k0) {
        short* Ks = (short*)(smem + buf*20480);
        short* Qs = (short*)(smem + buf*20480 + 16384);
#pragma unroll
        for (int r2 = 0; r2 < 4; r2++)
            gload16(Kp + (long long)(w*64 + r2*16 + srow)*ND + k0 + schk, &Ks[(w*64 + r2*16)*32]);
        gload16(Qp + (long long)(q0 + w*16 + srow)*ND + k0 + schk, &Qs[(w*16)*32]);
    };

    f32x4 acc[4][4];
#pragma unroll
    for (int i = 0; i < 4; i++)
#pragma unroll
        for (int j = 0; j < 4; j++) acc[i][j] = (f32x4){0.f,0.f,0.f,0.f};

    stage1(0, 0);
    for (int t = 0; t < 8; t++) {
        const int buf = t & 1;
        if (t + 1 < 8) {
            stage1(buf ^ 1, (t + 1) * 32);
            asm volatile("s_waitcnt vmcnt(5)" ::: "memory");
        } else {
            asm volatile("s_waitcnt vmcnt(0)" ::: "memory");
        }
        __builtin_amdgcn_s_barrier();
        __builtin_amdgcn_sched_barrier(0);
        const short* Ks = (const short*)(smem + buf*20480);
        const short* Qs = (const short*)(smem + buf*20480 + 16384);
        bf16x8 ak[4], bq[4];
#pragma unroll
        for (int i = 0; i < 4; i++) ak[i] = *(const bf16x8*)&Ks[(w*64 + i*16 + fr)*32 + RUNIT(qh, fr)];
#pragma unroll
        for (int j = 0; j < 4; j++) bq[j] = *(const bf16x8*)&Qs[(j*16 + fr)*32 + RUNIT(qh, fr)];
#pragma unroll
        for (int i = 0; i < 4; i++)
#pragma unroll
            for (int j = 0; j < 4; j++)
                acc[i][j] = MFMA(ak[i], bq[j], acc[i][j], 0, 0, 0);
        __builtin_amdgcn_s_barrier();
        __builtin_amdgcn_sched_barrier(0);
    }

    float mk[4][4];
#pragma unroll
    for (int i = 0; i < 4; i++)
#pragma unroll
        for (int rg = 0; rg < 4; rg++) mk[i][rg] = maskv[w*64 + i*16 + qh*4 + rg];
#pragma unroll
    for (int i = 0; i < 4; i++)
#pragma unroll
        for (int j = 0; j < 4; j++)
#pragma unroll
            for (int rg = 0; rg < 4; rg++)
                acc[i][j][rg] = acc[i][j][rg] * 0.0625f + mk[i][rg];

    float pm[4];
#pragma unroll
    for (int j = 0; j < 4; j++) {
        float m = -3.0e38f;
#pragma unroll
        for (int i = 0; i < 4; i++)
#pragma unroll
            for (int rg = 0; rg < 4; rg++) m = fmaxf(m, acc[i][j][rg]);
        m = fmaxf(m, __shfl_xor(m, 16));
        m = fmaxf(m, __shfl_xor(m, 32));
        pm[j] = m;
    }
#pragma unroll
    for (int j = 0; j < 4; j++) red[w*64 + j*16 + fr] = pm[j];
    __syncthreads();
    float gm[4];
#pragma unroll
    for (int j = 0; j < 4; j++)
        gm[j] = fmaxf(fmaxf(red[j*16 + fr], red[64 + j*16 + fr]),
                      fmaxf(red[128 + j*16 + fr], red[192 + j*16 + fr]));
    float ps[4] = {0.f, 0.f, 0.f, 0.f};
#pragma unroll
    for (int i = 0; i < 4; i++)
#pragma unroll
        for (int j = 0; j < 4; j++)
#pragma unroll
            for (int rg = 0; rg < 4; rg++) {
                float e = __expf(acc[i][j][rg] - gm[j]);
                acc[i][j][rg] = e;
                ps[j] += e;
            }
#pragma unroll
    for (int j = 0; j < 4; j++) {
        ps[j] += __shfl_xor(ps[j], 16);
        ps[j] += __shfl_xor(ps[j], 32);
    }
    __syncthreads();
#pragma unroll
    for (int j = 0; j < 4; j++) red[w*64 + j*16 + fr] = ps[j];
    __syncthreads();
    float inv[4];
#pragma unroll
    for (int j = 0; j < 4; j++)
        inv[j] = 1.f / (red[j*16 + fr] + red[64 + j*16 + fr] + red[128 + j*16 + fr] + red[192 + j*16 + fr]);

#pragma unroll
    for (int i = 0; i < 4; i++)
#pragma unroll
        for (int j = 0; j < 4; j++) {
            ushort4 pk;
            pk.x = fbits(acc[i][j][0] * inv[j]);
            pk.y = fbits(acc[i][j][1] * inv[j]);
            pk.z = fbits(acc[i][j][2] * inv[j]);
            pk.w = fbits(acc[i][j][3] * inv[j]);
            *(ushort4*)&P[(j*16 + fr)*PSTR + w*64 + i*16 + qh*4] = pk;
        }
    __syncthreads();

    auto stage2 = [&](int buf, int s0) {
        short* Vs = (short*)(smem + buf*20480);
#pragma unroll
        for (int r2 = 0; r2 < 4; r2++)
            gload16(Vp + (long long)(w*64 + r2*16 + srow)*SP + s0 + schk, &Vs[(w*64 + r2*16)*32]);
    };

    f32x4 acc2[4][4];
#pragma unroll
    for (int i = 0; i < 4; i++)
#pragma unroll
        for (int j = 0; j < 4; j++) acc2[i][j] = (f32x4){0.f,0.f,0.f,0.f};

    stage2(0, 0);
    for (int t = 0; t < 7; t++) {
        const int buf = t & 1;
        if (t + 1 < 7) {
            stage2(buf ^ 1, (t + 1) * 32);
            asm volatile("s_waitcnt vmcnt(4)" ::: "memory");
        } else {
            asm volatile("s_waitcnt vmcnt(0)" ::: "memory");
        }
        __builtin_amdgcn_s_barrier();
        __builtin_amdgcn_sched_barrier(0);
        const short* Vs = (const short*)(smem + buf*20480);
        bf16x8 ap[4], bv[4];
#pragma unroll
        for (int i = 0; i < 4; i++) ap[i] = *(const bf16x8*)&P[(i*16 + fr)*PSTR + t*32 + kc];
#pragma unroll
        for (int j = 0; j < 4; j++) bv[j] = *(const bf16x8*)&Vs[(w*64 + j*16 + fr)*32 + RUNIT(qh, fr)];
#pragma unroll
        for (int i = 0; i < 4; i++)
#pragma unroll
            for (int j = 0; j < 4; j++)
                acc2[i][j] = MFMA(ap[i], bv[j], acc2[i][j], 0, 0, 0);
        __builtin_amdgcn_s_barrier();
        __builtin_amdgcn_sched_barrier(0);
    }

#pragma unroll
    for (int i = 0; i < 4; i++)
#pragma unroll
        for (int j = 0; j < 4; j++)
#pragma unroll
            for (int rg = 0; rg < 4; rg++) {
                const int qg = q0 + i*16 + qh*4 + rg;
                if (qg < NS) {
                    const int d = w*64 + j*16 + fr;
                    ctx[((long long)(b*NS + qg))*1536 + h*256 + d] = f2b(acc2[i][j][rg]);
                }
            }
}

// ---------------------------------------------------------------------------
__global__ void embed_kernel(const int* __restrict__ tokens, const float* __restrict__ tok_emb,
                             const float* __restrict__ pos_emb, float* __restrict__ hf,
                             bf16* __restrict__ hbf)
{
    long long q = (long long)blockIdx.x * 256 + threadIdx.x;   // quad index
    if (q >= (long long)NBS * 64) return;
    long long r = q >> 6;
    int j = (int)(q & 63) * 4;
    int tk = tokens[r];
    int s  = (int)(r % NS);
    float4 tv = *(const float4*)(tok_emb + (long long)tk * ND + j);
    float4 pv = *(const float4*)(pos_emb + s * ND + j);
    float4 v = make_float4(tv.x+pv.x, tv.y+pv.y, tv.z+pv.z, tv.w+pv.w);
    *(float4*)(hf + r*ND + j) = v;
    ushort4 pk;
    pk.x = fbits(v.x); pk.y = fbits(v.y); pk.z = fbits(v.z); pk.w = fbits(v.w);
    *(ushort4*)(hbf + r*ND + j) = pk;
}

// Tiled transpose: out[l][c*outStride + r] = in[l][r*C + c]  (f32 -> bf16)
__global__ __launch_bounds__(256)
void transpose_tile(const float* __restrict__ in, bf16* __restrict__ out,
                    int R, int C, long long inL, long long outL, int outStride)
{
    __shared__ float tl[32][33];
    const int l  = blockIdx.z;
    const int r0 = blockIdx.y * 32, c0 = blockIdx.x * 32;
    const float* ip = in + (long long)l * inL;
    bf16* op = out + (long long)l * outL;
    const int tx = threadIdx.x & 31, ty = threadIdx.x >> 5;
#pragma unroll
    for (int i = 0; i < 4; i++) {
        const int r = r0 + ty + i*8;
        tl[ty + i*8][tx] = ip[(long long)r * C + c0 + tx];
    }
    __syncthreads();
#pragma unroll
    for (int i = 0; i < 4; i++) {
        const int c = c0 + ty + i*8;
        op[(long long)c * outStride + r0 + tx] = f2b(tl[tx][ty + i*8]);
    }
}

__global__ __launch_bounds__(256)
void build_wtns(const float* __restrict__ A1, const float* __restrict__ A2,
                const float* __restrict__ A3, const float* __restrict__ A4,
                bf16* __restrict__ wcat)
{
    int lx = blockIdx.x;
    __shared__ float a1s[32], a2s[128], a3s[128], a4s[32];
    int t = threadIdx.x;
    if (t < 32)  { a1s[t] = A1[lx*32 + t]; a4s[t] = A4[lx*32 + t]; }
    if (t < 128) { a2s[t] = A2[lx*128 + t]; a3s[t] = A3[lx*128 + t]; }
    __syncthreads();
    int d = t;
    int p = d >> 6, q = (d >> 4) & 3, rr = (d >> 2) & 3, tt = d & 3;
    for (int i = 0; i < 4; i++) {
        float w1_0 = a1s[(p*2 + 0)*4 + i];
        float w1_1 = a1s[(p*2 + 1)*4 + i];
        for (int j = 0; j < 8; j++) {
            float c1_0 = w1_0 * a2s[((q*2+0)*2+0)*8 + j] + w1_1 * a2s[((q*2+1)*2+0)*8 + j];
            float c1_1 = w1_0 * a2s[((q*2+0)*2+1)*8 + j] + w1_1 * a2s[((q*2+1)*2+1)*8 + j];
            for (int kk = 0; kk < 8; kk++) {
                float c2_0 = c1_0 * a3s[((rr*2+0)*2+0)*8 + kk] + c1_1 * a3s[((rr*2+1)*2+0)*8 + kk];
                float c2_1 = c1_0 * a3s[((rr*2+0)*2+1)*8 + kk] + c1_1 * a3s[((rr*2+1)*2+1)*8 + kk];
                for (int ll = 0; ll < 4; ll++) {
                    float sv = c2_0 * a4s[(tt*2 + 0)*4 + ll] + c2_1 * a4s[(tt*2 + 1)*4 + ll];
                    int e = ((i*8 + j)*8 + kk)*4 + ll;
                    wcat[((long long)lx * 1536 + 512 + e) * 256 + d] = f2b(sv);
                }
            }
        }
    }
}

// out = LN(resid + raw0 + raw1 + bias) * g + b  (float4 vectorized)
__global__ __launch_bounds__(256)
void ln_kernel(const float* __restrict__ raw0, const float* __restrict__ raw1,
               const float* __restrict__ bias, const float* __restrict__ resid,
               const float* __restrict__ g, const float* __restrict__ bb,
               float* __restrict__ outF, bf16* __restrict__ outBf)
{
    int w = threadIdx.x >> 6, lane = threadIdx.x & 63;
    long long r = (long long)blockIdx.x * 4 + w;
    long long base = r * ND + lane * 4;
    float4 x  = *(const float4*)(resid + base);
    float4 y0 = *(const float4*)(raw0 + base);
    float4 y1 = *(const float4*)(raw1 + base);
    float4 bs = *(const float4*)(bias + lane * 4);
    x.x += y0.x + y1.x + bs.x;
    x.y += y0.y + y1.y + bs.y;
    x.z += y0.z + y1.z + bs.z;
    x.w += y0.w + y1.w + bs.w;
    float s = x.x + x.y + x.z + x.w;
#pragma unroll
    for (int o = 32; o; o >>= 1) s += __shfl_xor(s, o);
    float mean = s * (1.f/256.f);
    float vs = (x.x-mean)*(x.x-mean) + (x.y-mean)*(x.y-mean)
             + (x.z-mean)*(x.z-mean) + (x.w-mean)*(x.w-mean);
#pragma unroll
    for (int o = 32; o; o >>= 1) vs += __shfl_xor(vs, o);
    float rs = rsqrtf(vs * (1.f/256.f) + 1e-6f);
    float4 gv = *(const float4*)(g  + lane * 4);
    float4 bv = *(const float4*)(bb + lane * 4);
    float4 o4;
    o4.x = (x.x - mean) * rs * gv.x + bv.x;
    o4.y = (x.y - mean) * rs * gv.y + bv.y;
    o4.z = (x.z - mean) * rs * gv.z + bv.z;
    o4.w = (x.w - mean) * rs * gv.w + bv.w;
    *(float4*)(outF + base) = o4;
    ushort4 pk;
    pk.x = fbits(o4.x); pk.y = fbits(o4.y); pk.z = fbits(o4.z); pk.w = fbits(o4.w);
    *(ushort4*)(outBf + base) = pk;
}

// ---------------------------------------------------------------------------
extern "C" void kernel_launch(void* const* d_in, const int* in_sizes, int n_in,
                              void* d_out, int out_size, void* d_ws, size_t ws_size,
                              hipStream_t stream)
{
    const int*   tokens  = (const int*)  d_in[0];
    const float* tok_emb = (const float*)d_in[1];
    const float* pos_emb = (const float*)d_in[2];
    const float* wqkv_w  = (const float*)d_in[3];
    const float* wqkv_b  = (const float*)d_in[4];
    const float* A1      = (const float*)d_in[5];
    const float* A2      = (const float*)d_in[6];
    const float* A3      = (const float*)d_in[7];
    const float* A4      = (const float*)d_in[8];
    const float* tnb     = (const float*)d_in[9];
    const float* out_w   = (const float*)d_in[10];
    const float* out_b   = (const float*)d_in[11];
    const float* ff1_w   = (const float*)d_in[12];
    const float* ff1_b   = (const float*)d_in[13];
    const float* ff2_w   = (const float*)d_in[14];
    const float* ff2_b   = (const float*)d_in[15];
    const float* ln1_g   = (const float*)d_in[16];
    const float* ln1_b   = (const float*)d_in[17];
    const float* ln2_g   = (const float*)d_in[18];
    const float* ln2_b   = (const float*)d_in[19];

    char* ws = (char*)d_ws;
    size_t off = 0;
    auto alloc = [&](size_t bytes) -> char* {
        char* p = ws + off;
        off += (bytes + 255) & ~(size_t)255;
        return p;
    };
    float* hf    = (float*)alloc((size_t)NBS * ND * 4);
    bf16*  hbf   = (bf16*) alloc((size_t)NBS * ND * 2);
    bf16*  wcat  = (bf16*) alloc(24ull * 1536 * 256 * 2);
    bf16*  owt   = (bf16*) alloc(8ull * 256 * 1536 * 2);
    bf16*  f1wt  = (bf16*) alloc(8ull * 1024 * 256 * 2);
    bf16*  f2wt  = (bf16*) alloc(8ull * 256 * 1024 * 2);
    bf16*  Qb    = (bf16*) alloc((size_t)NZ * SLAB * 2);
    bf16*  Kb    = (bf16*) alloc((size_t)NZ * SLAB * 2);
    bf16*  Vtb   = (bf16*) alloc((size_t)NZ * SLAB * 2);
    bf16*  ctxg  = (bf16*) alloc((size_t)NBS * 1536 * 2);
    bf16*  ffn   = (bf16*) alloc((size_t)NBS * 1024 * 2);
    float* raw   = (float*)alloc((size_t)NBS * ND * 4 * 2);   // 2 split-K partials
    float* out1f = (float*)alloc((size_t)NBS * ND * 4);
    bf16*  out1bf= (bf16*) alloc((size_t)NBS * ND * 2);
    if (off > ws_size) return;
    float* raw1 = raw + (size_t)NBS * ND;

    // No memset of Q/K/Vt pads. Pad content (poison) is inert: K-pads are
    // masked (-1e9 -> exp underflows to exactly 0), P[s>=200]==0 multiplies
    // Vt-pad garbage to 0, and pad-q outputs are never stored (qg<NS guard).

    embed_kernel<<<1600, 256, 0, stream>>>(tokens, tok_emb, pos_emb, hf, hbf);
    transpose_tile<<<dim3(16, 8, 24), 256, 0, stream>>>(
        wqkv_w, wcat, 256, 512, 256ll*512, 1536ll*256, 256);
    build_wtns<<<24, 256, 0, stream>>>(A1, A2, A3, A4, wcat);
    transpose_tile<<<dim3(8, 48, 8), 256, 0, stream>>>(
        out_w, owt, 1536, 256, 1536ll*256, 256ll*1536, 1536);
    transpose_tile<<<dim3(32, 8, 8), 256, 0, stream>>>(
        ff1_w, f1wt, 256, 1024, 256ll*1024, 1024ll*256, 256);
    transpose_tile<<<dim3(8, 32, 8), 256, 0, stream>>>(
        ff2_w, f2wt, 1024, 256, 1024ll*256, 256ll*1024, 1024);

    for (int l = 0; l < NL; l++) {
        const bf16* wl = wcat + (long long)l * 3 * 1536 * 256;
        // merged QKV v2: 64 dims x 256 tokens per block
        gemm_qkv<<<dim3(25, 72, 1), 256, 0, stream>>>(
            wl, hbf, wqkv_b + l * 3 * 512, tnb + l * 3 * 1024, Qb, Kb, Vtb);
        // fused attention -> ctxg [6400][1536]
        attn_fused<<<dim3(NZ, 4), 256, 0, stream>>>(Qb, Kb, Vtb, tokens, ctxg);
        // out projection, split-K=2 partials (no atomics)
        gemm_nt<EPI_F32><<<dim3(2, 50, 2), 256, 0, stream>>>(
            ctxg, owt + (long long)l * 256 * 1536, NBS, 256, 1536, 768, (long long)NBS*ND,
            raw, nullptr, nullptr);
        ln_kernel<<<1600, 256, 0, stream>>>(raw, raw1, out_b + l * 256, hf,
                                            ln1_g + l * 256, ln1_b + l * 256, out1f, out1bf);
        // FFN
        gemm_nt<EPI_RELU_BF><<<dim3(8, 50, 1), 256, 0, stream>>>(
            out1bf, f1wt + (long long)l * 1024 * 256, NBS, 1024, 256, 256, 0,
            nullptr, ffn, ff1_b + l * 1024);
        gemm_nt<EPI_F32><<<dim3(2, 50, 2), 256, 0, stream>>>(
            ffn, f2wt + (long long)l * 256 * 1024, NBS, 256, 1024, 512, (long long)NBS*ND,
            raw, nullptr, nullptr);
        ln_kernel<<<1600, 256, 0, stream>>>(raw, raw1, ff2_b + l * 256, out1f,
                                            ln2_g + l * 256, ln2_b + l * 256,
                                            (l == NL - 1) ? (float*)d_out : hf, hbf);
    }
}

// Round 15
// 964.541 us; speedup vs baseline: 1.0231x; 1.0231x over previous
//
#include <hip/hip_runtime.h>
#include <hip/hip_bf16.h>

typedef __bf16 bf16x8 __attribute__((ext_vector_type(8)));
typedef float f32x4 __attribute__((ext_vector_type(4)));
typedef int i32x4 __attribute__((ext_vector_type(4)));

#define NB 32
#define NS 200
#define SP 256
#define ND 256
#define NH 6
#define NL 8
#define NBS (NB*NS)      // 6400
#define NZ (NB*NH)       // 192
#define SLAB (SP*ND)     // 65536
#define PSTR 264         // P lds row stride (shorts)

using bf16 = __hip_bfloat16;

enum { EPI_F32 = 0, EPI_RELU_BF = 1 };

__device__ __forceinline__ float b2f(bf16 x) { return __bfloat162float(x); }
__device__ __forceinline__ bf16 f2b(float x) { return __float2bfloat16(x); }
__device__ __forceinline__ unsigned short fbits(float x) { bf16 h = f2b(x); return *(unsigned short*)&h; }

#define MFMA __builtin_amdgcn_mfma_f32_16x16x32_bf16

// async global->LDS, 16B per lane. LDS dest must be wave-uniform base (HW adds lane*16).
__device__ __forceinline__ void gload16(const bf16* g, const short* l) {
    __builtin_amdgcn_global_load_lds(
        (const __attribute__((address_space(1))) unsigned int*)(unsigned long long)(g),
        (__attribute__((address_space(3))) unsigned int*)(unsigned long long)(l), 16, 0, 0);
}

// LDS swizzle: rows are 64B = 4 x 16B units; XOR unit with (row>>1)&3 -> 2-way/bank (free).
// gload_lds dest is linear, so apply the permutation on the per-lane GLOBAL source (m173).
#define GUNIT(lane) ((((lane) & 3) ^ (((lane) >> 3) & 3)) * 8)
#define RUNIT(kcu, fr) ((((kcu) ^ (((fr) >> 1) & 3))) * 8)

// ---------------------------------------------------------------------------
// QKV GEMM (r13-proven): 64x64 tile, 4 waves (2x2), wave-tile 32x32, swizzled
// LDS. 4 LDS bufs, stage-ahead D=2, ONE barrier/iter.
// Epilogue: Q/K via LDS transpose -> 128B-coalesced stores; V direct (32B segs).
// ---------------------------------------------------------------------------
__global__ __launch_bounds__(256)
void gemm_qkv(const bf16* __restrict__ A, const bf16* __restrict__ Bm,
              const float* __restrict__ qkvb, const float* __restrict__ tnbp,
              bf16* __restrict__ Qb, bf16* __restrict__ Kb, bf16* __restrict__ Vb)
{
    __shared__ __align__(16) char smem[32768];
    short* Asl0 = (short*)smem;                 // [4][64*32]
    short* Bsl0 = (short*)(smem + 16384);       // [4][64*32]
    const int K = 256;
    const int tid  = threadIdx.x;
    const int m0   = blockIdx.y * 64;
    const int n0   = blockIdx.x * 64;
    const int lane = tid & 63, w = tid >> 6;
    const int wm   = (w >> 1) * 32, wn = (w & 1) * 32;
    const int fr   = lane & 15, kcu = lane >> 4;
    const int srow = lane >> 2, schk = GUNIT(lane);

    const bf16* Ag = A  + (long long)m0 * K;
    const bf16* Bg = Bm + (long long)n0 * K;

    f32x4 acc[2][2];
#pragma unroll
    for (int i = 0; i < 2; i++)
#pragma unroll
        for (int j = 0; j < 2; j++) acc[i][j] = (f32x4){0.f,0.f,0.f,0.f};

    auto stage = [&](int buf, int k0) {
        gload16(Ag + (long long)(w*16 + srow)*K + k0 + schk, &Asl0[buf*2048 + (w*16)*32]);
        gload16(Bg + (long long)(w*16 + srow)*K + k0 + schk, &Bsl0[buf*2048 + (w*16)*32]);
    };

    stage(0, 0);
    stage(1, 32);
    for (int t = 0; t < 8; t++) {
        const int buf = t & 3;
        if (t + 2 < 8) {
            stage((t + 2) & 3, (t + 2) * 32);
            asm volatile("s_waitcnt vmcnt(4)" ::: "memory");   // tiles t+1,t+2 in flight; t landed
        } else if (t + 1 < 8) {
            asm volatile("s_waitcnt vmcnt(2)" ::: "memory");
        } else {
            asm volatile("s_waitcnt vmcnt(0)" ::: "memory");
        }
        __builtin_amdgcn_s_barrier();
        __builtin_amdgcn_sched_barrier(0);
        bf16x8 af[2], bfm[2];
#pragma unroll
        for (int i = 0; i < 2; i++) af[i]  = *(const bf16x8*)&Asl0[buf*2048 + (wm + i*16 + fr)*32 + RUNIT(kcu, fr)];
#pragma unroll
        for (int j = 0; j < 2; j++) bfm[j] = *(const bf16x8*)&Bsl0[buf*2048 + (wn + j*16 + fr)*32 + RUNIT(kcu, fr)];
#pragma unroll
        for (int i = 0; i < 2; i++)
#pragma unroll
            for (int j = 0; j < 2; j++)
                acc[i][j] = MFMA(af[i], bfm[j], acc[i][j], 0, 0, 0);
        // no trailing barrier: 4-buf D=2 single-barrier schedule (skew<=1 iter)
    }

    const int xq   = m0 / 1536;          // uniform per block (1536 % 64 == 0)
    const int c1_0 = m0 - xq*1536;
    const int hdq  = c1_0 >> 8;          // 64-dim tile never crosses a head boundary
    const int ddb  = c1_0 & 255;

    if (xq < 2) {
        // ---- LDS-transpose epilogue: T[token][dim], stride 72 shorts
        short* T = (short*)smem;
        __syncthreads();                  // staging bufs dead; reuse
#pragma unroll
        for (int i = 0; i < 2; i++) {
            const int dl0 = wm + i*16 + kcu*4;     // local dim of rg=0
            float bv[4];
#pragma unroll
            for (int rg = 0; rg < 4; rg++) {
                const int cc = c1_0 + dl0 + rg;
                bv[rg] = (cc < 512) ? qkvb[xq*512 + cc] : tnbp[xq*1024 + cc - 512];
            }
#pragma unroll
            for (int j = 0; j < 2; j++) {
                const int tok = wn + j*16 + fr;
                ushort4 pk;
                pk.x = fbits(acc[i][j][0] + bv[0]);
                pk.y = fbits(acc[i][j][1] + bv[1]);
                pk.z = fbits(acc[i][j][2] + bv[2]);
                pk.w = fbits(acc[i][j][3] + bv[3]);
                *(ushort4*)&T[tok*72 + dl0] = pk;
            }
        }
        __syncthreads();
        const int tt = tid >> 2;          // local token
        const int dc = (tid & 3) * 16;    // local dim chunk (32B)
        const int c  = n0 + tt;
        const int bb = c / NS, ss = c - bb*NS;
        bf16* dst = xq ? Kb : Qb;
        bf16* dp  = dst + ((long long)((bb*NH + hdq)*SP + ss))*ND + ddb + dc;
        *(i32x4*)dp       = *(const i32x4*)&T[tt*72 + dc];
        *(i32x4*)(dp + 8) = *(const i32x4*)&T[tt*72 + dc + 8];
    } else {
        // ---- V: Vt[z][d][s], rg spans d -> stride SP; 16 lanes -> 32B segments
#pragma unroll
        for (int i = 0; i < 2; i++) {
            const int dl0 = wm + i*16 + kcu*4;
            float bv[4];
#pragma unroll
            for (int rg = 0; rg < 4; rg++) {
                const int cc = c1_0 + dl0 + rg;
                bv[rg] = (cc < 512) ? qkvb[2*512 + cc] : tnbp[2*1024 + cc - 512];
            }
#pragma unroll
            for (int j = 0; j < 2; j++) {
                const int c = n0 + wn + j*16 + fr;
                const int bb = c / NS, ss = c - bb*NS;
                const long long base = ((long long)((bb*NH + hdq)*ND + ddb + dl0))*SP + ss;
#pragma unroll
                for (int rg = 0; rg < 4; rg++)
                    Vb[base + (long long)rg*SP] = f2b(acc[i][j][rg] + bv[rg]);
            }
        }
    }
}

// ---------------------------------------------------------------------------
// NT GEMM 128x128 for outproj / ff1 / ff2 (r11-proven).
// 3 LDS bufs, D=1, ONE barrier/iter. blockIdx.z = split-K chunk.
// ---------------------------------------------------------------------------
template<int MODE>
__global__ __launch_bounds__(256)
void gemm_nt(const bf16* __restrict__ A, const bf16* __restrict__ Bm,
             int M, int N, int K, int Kspan, long long sOz,
             float* __restrict__ outF, bf16* __restrict__ outBf,
             const float* __restrict__ bias)
{
    __shared__ short Asl[3][128*32];
    __shared__ short Bsl[3][128*32];
    const int tid  = threadIdx.x;
    const int m0   = blockIdx.y * 128;
    const int n0   = blockIdx.x * 128;
    const int kbase= blockIdx.z * Kspan;
    const int lane = tid & 63, w = tid >> 6;
    const int wm   = (w >> 1) * 64, wn = (w & 1) * 64;
    const int fr   = lane & 15, kc = (lane >> 4) * 8;
    const int srow = lane >> 2, schk = (lane & 3) * 8;

    const bf16* Ag = A  + (long long)m0 * K + kbase;
    const bf16* Bg = Bm + (long long)n0 * K + kbase;

    f32x4 acc[4][4];
#pragma unroll
    for (int i = 0; i < 4; i++)
#pragma unroll
        for (int j = 0; j < 4; j++) acc[i][j] = (f32x4){0.f,0.f,0.f,0.f};

    auto stage = [&](int buf, int k0) {
        gload16(Ag + (long long)(w*32      + srow)*K + k0 + schk, &Asl[buf][(w*32     )*32]);
        gload16(Ag + (long long)(w*32 + 16 + srow)*K + k0 + schk, &Asl[buf][(w*32 + 16)*32]);
        gload16(Bg + (long long)(w*32      + srow)*K + k0 + schk, &Bsl[buf][(w*32     )*32]);
        gload16(Bg + (long long)(w*32 + 16 + srow)*K + k0 + schk, &Bsl[buf][(w*32 + 16)*32]);
    };

    const int nt = Kspan >> 5;
    stage(0, 0);
    for (int t = 0; t < nt; t++) {
        const int buf = t % 3;
        if (t + 1 < nt) {
            stage((t + 1) % 3, (t + 1) * 32);
            asm volatile("s_waitcnt vmcnt(4)" ::: "memory");
        } else {
            asm volatile("s_waitcnt vmcnt(0)" ::: "memory");
        }
        __builtin_amdgcn_s_barrier();
        __builtin_amdgcn_sched_barrier(0);
        bf16x8 af[4], bfm[4];
#pragma unroll
        for (int i = 0; i < 4; i++) af[i]  = *(const bf16x8*)&Asl[buf][(wm + i*16 + fr)*32 + kc];
#pragma unroll
        for (int j = 0; j < 4; j++) bfm[j] = *(const bf16x8*)&Bsl[buf][(wn + j*16 + fr)*32 + kc];
#pragma unroll
        for (int i = 0; i < 4; i++)
#pragma unroll
            for (int j = 0; j < 4; j++)
                acc[i][j] = MFMA(af[i], bfm[j], acc[i][j], 0, 0, 0);
    }

    const int rq = (lane >> 4) * 4;
#pragma unroll
    for (int i = 0; i < 4; i++) {
        const int r0 = m0 + wm + i*16 + rq;
#pragma unroll
        for (int j = 0; j < 4; j++) {
            const int c = n0 + wn + j*16 + fr;
            if (MODE == EPI_F32) {
#pragma unroll
                for (int rg = 0; rg < 4; rg++)
                    outF[(long long)blockIdx.z * sOz + (long long)(r0+rg)*N + c] = acc[i][j][rg];
            } else {
                const float bv = bias[c];
#pragma unroll
                for (int rg = 0; rg < 4; rg++)
                    outBf[(long long)(r0+rg)*N + c] = f2b(fmaxf(acc[i][j][rg] + bv, 0.f));
            }
        }
    }
}

// ---------------------------------------------------------------------------
// Fused attention (r11-proven): block = (z, 64-query quarter); grid (192, 4).
// ---------------------------------------------------------------------------
__global__ __launch_bounds__(256)
void attn_fused(const bf16* __restrict__ Qb, const bf16* __restrict__ Kb,
                const bf16* __restrict__ Vtb, const int* __restrict__ tokens,
                bf16* __restrict__ ctx)
{
    __shared__ __align__(16) char smem[2*20480 + 1024 + 1024 + 64*PSTR*2];
    float* red   = (float*)(smem + 40960);
    float* maskv = (float*)(smem + 40960 + 1024);
    short* P     = (short*)(smem + 40960 + 2048);

    const int z  = blockIdx.x;
    const int b  = z / NH, h = z - b*NH;
    const int q0 = blockIdx.y * 64;
    const int tid = threadIdx.x;
    const int lane = tid & 63, w = tid >> 6;
    const int fr = lane & 15, qh = lane >> 4;
    const int kc = qh * 8;
    const int srow = lane >> 2, schk = GUNIT(lane);

    const bf16* Kp = Kb  + (long long)z * SLAB;
    const bf16* Qp = Qb  + (long long)z * SLAB;
    const bf16* Vp = Vtb + (long long)z * SLAB;

    {
        const int s = tid;
        float mv = -1e9f;
        if (s < NS && tokens[b*NS + s] != 0) mv = 0.f;
        maskv[s] = mv;
    }

    auto stage1 = [&](int buf, int k0) {
        short* Ks = (short*)(smem + buf*20480);
        short* Qs = (short*)(smem + buf*20480 + 16384);
#pragma unroll
        for (int r2 = 0; r2 < 4; r2++)
            gload16(Kp + (long long)(w*64 + r2*16 + srow)*ND + k0 + schk, &Ks[(w*64 + r2*16)*32]);
        gload16(Qp + (long long)(q0 + w*16 + srow)*ND + k0 + schk, &Qs[(w*16)*32]);
    };

    f32x4 acc[4][4];
#pragma unroll
    for (int i = 0; i < 4; i++)
#pragma unroll
        for (int j = 0; j < 4; j++) acc[i][j] = (f32x4){0.f,0.f,0.f,0.f};

    stage1(0, 0);
    for (int t = 0; t < 8; t++) {
        const int buf = t & 1;
        if (t + 1 < 8) {
            stage1(buf ^ 1, (t + 1) * 32);
            asm volatile("s_waitcnt vmcnt(5)" ::: "memory");
        } else {
            asm volatile("s_waitcnt vmcnt(0)" ::: "memory");
        }
        __builtin_amdgcn_s_barrier();
        __builtin_amdgcn_sched_barrier(0);
        const short* Ks = (const short*)(smem + buf*20480);
        const short* Qs = (const short*)(smem + buf*20480 + 16384);
        bf16x8 ak[4], bq[4];
#pragma unroll
        for (int i = 0; i < 4; i++) ak[i] = *(const bf16x8*)&Ks[(w*64 + i*16 + fr)*32 + RUNIT(qh, fr)];
#pragma unroll
        for (int j = 0; j < 4; j++) bq[j] = *(const bf16x8*)&Qs[(j*16 + fr)*32 + RUNIT(qh, fr)];
#pragma unroll
        for (int i = 0; i < 4; i++)
#pragma unroll
            for (int j = 0; j < 4; j++)
                acc[i][j] = MFMA(ak[i], bq[j], acc[i][j], 0, 0, 0);
        __builtin_amdgcn_s_barrier();
        __builtin_amdgcn_sched_barrier(0);
    }

    float mk[4][4];
#pragma unroll
    for (int i = 0; i < 4; i++)
#pragma unroll
        for (int rg = 0; rg < 4; rg++) mk[i][rg] = maskv[w*64 + i*16 + qh*4 + rg];
#pragma unroll
    for (int i = 0; i < 4; i++)
#pragma unroll
        for (int j = 0; j < 4; j++)
#pragma unroll
            for (int rg = 0; rg < 4; rg++)
                acc[i][j][rg] = acc[i][j][rg] * 0.0625f + mk[i][rg];

    float pm[4];
#pragma unroll
    for (int j = 0; j < 4; j++) {
        float m = -3.0e38f;
#pragma unroll
        for (int i = 0; i < 4; i++)
#pragma unroll
            for (int rg = 0; rg < 4; rg++) m = fmaxf(m, acc[i][j][rg]);
        m = fmaxf(m, __shfl_xor(m, 16));
        m = fmaxf(m, __shfl_xor(m, 32));
        pm[j] = m;
    }
#pragma unroll
    for (int j = 0; j < 4; j++) red[w*64 + j*16 + fr] = pm[j];
    __syncthreads();
    float gm[4];
#pragma unroll
    for (int j = 0; j < 4; j++)
        gm[j] = fmaxf(fmaxf(red[j*16 + fr], red[64 + j*16 + fr]),
                      fmaxf(red[128 + j*16 + fr], red[192 + j*16 + fr]));
    float ps[4] = {0.f, 0.f, 0.f, 0.f};
#pragma unroll
    for (int i = 0; i < 4; i++)
#pragma unroll
        for (int j = 0; j < 4; j++)
#pragma unroll
            for (int rg = 0; rg < 4; rg++) {
                float e = __expf(acc[i][j][rg] - gm[j]);
                acc[i][j][rg] = e;
                ps[j] += e;
            }
#pragma unroll
    for (int j = 0; j < 4; j++) {
        ps[j] += __shfl_xor(ps[j], 16);
        ps[j] += __shfl_xor(ps[j], 32);
    }
    __syncthreads();
#pragma unroll
    for (int j = 0; j < 4; j++) red[w*64 + j*16 + fr] = ps[j];
    __syncthreads();
    float inv[4];
#pragma unroll
    for (int j = 0; j < 4; j++)
        inv[j] = 1.f / (red[j*16 + fr] + red[64 + j*16 + fr] + red[128 + j*16 + fr] + red[192 + j*16 + fr]);

#pragma unroll
    for (int i = 0; i < 4; i++)
#pragma unroll
        for (int j = 0; j < 4; j++) {
            ushort4 pk;
            pk.x = fbits(acc[i][j][0] * inv[j]);
            pk.y = fbits(acc[i][j][1] * inv[j]);
            pk.z = fbits(acc[i][j][2] * inv[j]);
            pk.w = fbits(acc[i][j][3] * inv[j]);
            *(ushort4*)&P[(j*16 + fr)*PSTR + w*64 + i*16 + qh*4] = pk;
        }
    __syncthreads();

    auto stage2 = [&](int buf, int s0) {
        short* Vs = (short*)(smem + buf*20480);
#pragma unroll
        for (int r2 = 0; r2 < 4; r2++)
            gload16(Vp + (long long)(w*64 + r2*16 + srow)*SP + s0 + schk, &Vs[(w*64 + r2*16)*32]);
    };

    f32x4 acc2[4][4];
#pragma unroll
    for (int i = 0; i < 4; i++)
#pragma unroll
        for (int j = 0; j < 4; j++) acc2[i][j] = (f32x4){0.f,0.f,0.f,0.f};

    stage2(0, 0);
    for (int t = 0; t < 7; t++) {
        const int buf = t & 1;
        if (t + 1 < 7) {
            stage2(buf ^ 1, (t + 1) * 32);
            asm volatile("s_waitcnt vmcnt(4)" ::: "memory");
        } else {
            asm volatile("s_waitcnt vmcnt(0)" ::: "memory");
        }
        __builtin_amdgcn_s_barrier();
        __builtin_amdgcn_sched_barrier(0);
        const short* Vs = (const short*)(smem + buf*20480);
        bf16x8 ap[4], bv[4];
#pragma unroll
        for (int i = 0; i < 4; i++) ap[i] = *(const bf16x8*)&P[(i*16 + fr)*PSTR + t*32 + kc];
#pragma unroll
        for (int j = 0; j < 4; j++) bv[j] = *(const bf16x8*)&Vs[(w*64 + j*16 + fr)*32 + RUNIT(qh, fr)];
#pragma unroll
        for (int i = 0; i < 4; i++)
#pragma unroll
            for (int j = 0; j < 4; j++)
                acc2[i][j] = MFMA(ap[i], bv[j], acc2[i][j], 0, 0, 0);
        __builtin_amdgcn_s_barrier();
        __builtin_amdgcn_sched_barrier(0);
    }

#pragma unroll
    for (int i = 0; i < 4; i++)
#pragma unroll
        for (int j = 0; j < 4; j++)
#pragma unroll
            for (int rg = 0; rg < 4; rg++) {
                const int qg = q0 + i*16 + qh*4 + rg;
                if (qg < NS) {
                    const int d = w*64 + j*16 + fr;
                    ctx[((long long)(b*NS + qg))*1536 + h*256 + d] = f2b(acc2[i][j][rg]);
                }
            }
}

// ---------------------------------------------------------------------------
__global__ void embed_kernel(const int* __restrict__ tokens, const float* __restrict__ tok_emb,
                             const float* __restrict__ pos_emb, float* __restrict__ hf,
                             bf16* __restrict__ hbf)
{
    long long q = (long long)blockIdx.x * 256 + threadIdx.x;   // quad index
    if (q >= (long long)NBS * 64) return;
    long long r = q >> 6;
    int j = (int)(q & 63) * 4;
    int tk = tokens[r];
    int s  = (int)(r % NS);
    float4 tv = *(const float4*)(tok_emb + (long long)tk * ND + j);
    float4 pv = *(const float4*)(pos_emb + s * ND + j);
    float4 v = make_float4(tv.x+pv.x, tv.y+pv.y, tv.z+pv.z, tv.w+pv.w);
    *(float4*)(hf + r*ND + j) = v;
    ushort4 pk;
    pk.x = fbits(v.x); pk.y = fbits(v.y); pk.z = fbits(v.z); pk.w = fbits(v.w);
    *(ushort4*)(hbf + r*ND + j) = pk;
}

// Tiled transpose: out[l][c*outStride + r] = in[l][r*C + c]  (f32 -> bf16)
__global__ __launch_bounds__(256)
void transpose_tile(const float* __restrict__ in, bf16* __restrict__ out,
                    int R, int C, long long inL, long long outL, int outStride)
{
    __shared__ float tl[32][33];
    const int l  = blockIdx.z;
    const int r0 = blockIdx.y * 32, c0 = blockIdx.x * 32;
    const float* ip = in + (long long)l * inL;
    bf16* op = out + (long long)l * outL;
    const int tx = threadIdx.x & 31, ty = threadIdx.x >> 5;
#pragma unroll
    for (int i = 0; i < 4; i++) {
        const int r = r0 + ty + i*8;
        tl[ty + i*8][tx] = ip[(long long)r * C + c0 + tx];
    }
    __syncthreads();
#pragma unroll
    for (int i = 0; i < 4; i++) {
        const int c = c0 + ty + i*8;
        op[(long long)c * outStride + r0 + tx] = f2b(tl[tx][ty + i*8]);
    }
}

__global__ __launch_bounds__(256)
void build_wtns(const float* __restrict__ A1, const float* __restrict__ A2,
                const float* __restrict__ A3, const float* __restrict__ A4,
                bf16* __restrict__ wcat)
{
    int lx = blockIdx.x;
    __shared__ float a1s[32], a2s[128], a3s[128], a4s[32];
    int t = threadIdx.x;
    if (t < 32)  { a1s[t] = A1[lx*32 + t]; a4s[t] = A4[lx*32 + t]; }
    if (t < 128) { a2s[t] = A2[lx*128 + t]; a3s[t] = A3[lx*128 + t]; }
    __syncthreads();
    int d = t;
    int p = d >> 6, q = (d >> 4) & 3, rr = (d >> 2) & 3, tt = d & 3;
    for (int i = 0; i < 4; i++) {
        float w1_0 = a1s[(p*2 + 0)*4 + i];
        float w1_1 = a1s[(p*2 + 1)*4 + i];
        for (int j = 0; j < 8; j++) {
            float c1_0 = w1_0 * a2s[((q*2+0)*2+0)*8 + j] + w1_1 * a2s[((q*2+1)*2+0)*8 + j];
            float c1_1 = w1_0 * a2s[((q*2+0)*2+1)*8 + j] + w1_1 * a2s[((q*2+1)*2+1)*8 + j];
            for (int kk = 0; kk < 8; kk++) {
                float c2_0 = c1_0 * a3s[((rr*2+0)*2+0)*8 + kk] + c1_1 * a3s[((rr*2+1)*2+0)*8 + kk];
                float c2_1 = c1_0 * a3s[((rr*2+0)*2+1)*8 + kk] + c1_1 * a3s[((rr*2+1)*2+1)*8 + kk];
                for (int ll = 0; ll < 4; ll++) {
                    float sv = c2_0 * a4s[(tt*2 + 0)*4 + ll] + c2_1 * a4s[(tt*2 + 1)*4 + ll];
                    int e = ((i*8 + j)*8 + kk)*4 + ll;
                    wcat[((long long)lx * 1536 + 512 + e) * 256 + d] = f2b(sv);
                }
            }
        }
    }
}

// out = LN(resid + raw0..3 + bias) * g + b  (float4 vectorized, 4 partials)
__global__ __launch_bounds__(256)
void ln_kernel(const float* __restrict__ raw, long long pstride, int nparts,
               const float* __restrict__ bias, const float* __restrict__ resid,
               const float* __restrict__ g, const float* __restrict__ bb,
               float* __restrict__ outF, bf16* __restrict__ outBf)
{
    int w = threadIdx.x >> 6, lane = threadIdx.x & 63;
    long long r = (long long)blockIdx.x * 4 + w;
    long long base = r * ND + lane * 4;
    float4 x  = *(const float4*)(resid + base);
    float4 bs = *(const float4*)(bias + lane * 4);
    x.x += bs.x; x.y += bs.y; x.z += bs.z; x.w += bs.w;
#pragma unroll 4
    for (int p = 0; p < nparts; p++) {
        float4 y = *(const float4*)(raw + (long long)p * pstride + base);
        x.x += y.x; x.y += y.y; x.z += y.z; x.w += y.w;
    }
    float s = x.x + x.y + x.z + x.w;
#pragma unroll
    for (int o = 32; o; o >>= 1) s += __shfl_xor(s, o);
    float mean = s * (1.f/256.f);
    float vs = (x.x-mean)*(x.x-mean) + (x.y-mean)*(x.y-mean)
             + (x.z-mean)*(x.z-mean) + (x.w-mean)*(x.w-mean);
#pragma unroll
    for (int o = 32; o; o >>= 1) vs += __shfl_xor(vs, o);
    float rs = rsqrtf(vs * (1.f/256.f) + 1e-6f);
    float4 gv = *(const float4*)(g  + lane * 4);
    float4 bv = *(const float4*)(bb + lane * 4);
    float4 o4;
    o4.x = (x.x - mean) * rs * gv.x + bv.x;
    o4.y = (x.y - mean) * rs * gv.y + bv.y;
    o4.z = (x.z - mean) * rs * gv.z + bv.z;
    o4.w = (x.w - mean) * rs * gv.w + bv.w;
    *(float4*)(outF + base) = o4;
    ushort4 pk;
    pk.x = fbits(o4.x); pk.y = fbits(o4.y); pk.z = fbits(o4.z); pk.w = fbits(o4.w);
    *(ushort4*)(outBf + base) = pk;
}

// ---------------------------------------------------------------------------
extern "C" void kernel_launch(void* const* d_in, const int* in_sizes, int n_in,
                              void* d_out, int out_size, void* d_ws, size_t ws_size,
                              hipStream_t stream)
{
    const int*   tokens  = (const int*)  d_in[0];
    const float* tok_emb = (const float*)d_in[1];
    const float* pos_emb = (const float*)d_in[2];
    const float* wqkv_w  = (const float*)d_in[3];
    const float* wqkv_b  = (const float*)d_in[4];
    const float* A1      = (const float*)d_in[5];
    const float* A2      = (const float*)d_in[6];
    const float* A3      = (const float*)d_in[7];
    const float* A4      = (const float*)d_in[8];
    const float* tnb     = (const float*)d_in[9];
    const float* out_w   = (const float*)d_in[10];
    const float* out_b   = (const float*)d_in[11];
    const float* ff1_w   = (const float*)d_in[12];
    const float* ff1_b   = (const float*)d_in[13];
    const float* ff2_w   = (const float*)d_in[14];
    const float* ff2_b   = (const float*)d_in[15];
    const float* ln1_g   = (const float*)d_in[16];
    const float* ln1_b   = (const float*)d_in[17];
    const float* ln2_g   = (const float*)d_in[18];
    const float* ln2_b   = (const float*)d_in[19];

    char* ws = (char*)d_ws;
    size_t off = 0;
    auto alloc = [&](size_t bytes) -> char* {
        char* p = ws + off;
        off += (bytes + 255) & ~(size_t)255;
        return p;
    };
    float* hf    = (float*)alloc((size_t)NBS * ND * 4);
    bf16*  hbf   = (bf16*) alloc((size_t)NBS * ND * 2);
    bf16*  wcat  = (bf16*) alloc(24ull * 1536 * 256 * 2);
    bf16*  owt   = (bf16*) alloc(8ull * 256 * 1536 * 2);
    bf16*  f1wt  = (bf16*) alloc(8ull * 1024 * 256 * 2);
    bf16*  f2wt  = (bf16*) alloc(8ull * 256 * 1024 * 2);
    bf16*  Qb    = (bf16*) alloc((size_t)NZ * SLAB * 2);
    bf16*  Kb    = (bf16*) alloc((size_t)NZ * SLAB * 2);
    bf16*  Vtb   = (bf16*) alloc((size_t)NZ * SLAB * 2);
    bf16*  ctxg  = (bf16*) alloc((size_t)NBS * 1536 * 2);
    bf16*  ffn   = (bf16*) alloc((size_t)NBS * 1024 * 2);
    float* raw   = (float*)alloc((size_t)NBS * ND * 4 * 4);   // 4 split-K partials
    float* out1f = (float*)alloc((size_t)NBS * ND * 4);
    bf16*  out1bf= (bf16*) alloc((size_t)NBS * ND * 2);
    if (off > ws_size) return;
    const long long PS = (long long)NBS * ND;

    // No memset of Q/K/Vt pads. Pad content (poison) is inert: K-pads are
    // masked (-1e9 -> exp underflows to exactly 0), P[s>=200]==0 multiplies
    // Vt-pad garbage to 0, and pad-q outputs are never stored (qg<NS guard).

    embed_kernel<<<1600, 256, 0, stream>>>(tokens, tok_emb, pos_emb, hf, hbf);
    transpose_tile<<<dim3(16, 8, 24), 256, 0, stream>>>(
        wqkv_w, wcat, 256, 512, 256ll*512, 1536ll*256, 256);
    build_wtns<<<24, 256, 0, stream>>>(A1, A2, A3, A4, wcat);
    transpose_tile<<<dim3(8, 48, 8), 256, 0, stream>>>(
        out_w, owt, 1536, 256, 1536ll*256, 256ll*1536, 1536);
    transpose_tile<<<dim3(32, 8, 8), 256, 0, stream>>>(
        ff1_w, f1wt, 256, 1024, 256ll*1024, 1024ll*256, 256);
    transpose_tile<<<dim3(8, 32, 8), 256, 0, stream>>>(
        ff2_w, f2wt, 1024, 256, 1024ll*256, 256ll*1024, 1024);

    for (int l = 0; l < NL; l++) {
        const bf16* wl = wcat + (long long)l * 3 * 1536 * 256;
        // merged QKV: A = qkv weights [4608,256], B = activations [6400,256]
        gemm_qkv<<<dim3(100, 72, 1), 256, 0, stream>>>(
            wl, hbf, wqkv_b + l * 3 * 512, tnb + l * 3 * 1024, Qb, Kb, Vtb);
        // fused attention -> ctxg [6400][1536]
        attn_fused<<<dim3(NZ, 4), 256, 0, stream>>>(Qb, Kb, Vtb, tokens, ctxg);
        // out projection, split-K=4 partials (no atomics)
        gemm_nt<EPI_F32><<<dim3(2, 50, 4), 256, 0, stream>>>(
            ctxg, owt + (long long)l * 256 * 1536, NBS, 256, 1536, 384, PS,
            raw, nullptr, nullptr);
        ln_kernel<<<1600, 256, 0, stream>>>(raw, PS, 4, out_b + l * 256, hf,
                                            ln1_g + l * 256, ln1_b + l * 256, out1f, out1bf);
        // FFN
        gemm_nt<EPI_RELU_BF><<<dim3(8, 50, 1), 256, 0, stream>>>(
            out1bf, f1wt + (long long)l * 1024 * 256, NBS, 1024, 256, 256, 0,
            nullptr, ffn, ff1_b + l * 1024);
        gemm_nt<EPI_F32><<<dim3(2, 50, 4), 256, 0, stream>>>(
            ffn, f2wt + (long long)l * 256 * 1024, NBS, 256, 1024, 256, PS,
            raw, nullptr, nullptr);
        ln_kernel<<<1600, 256, 0, stream>>>(raw, PS, 4, ff2_b + l * 256, out1f,
                                            ln2_g + l * 256, ln2_b + l * 256,
                                            (l == NL - 1) ? (float*)d_out : hf, hbf);
    }
}

// Round 16
// 946.091 us; speedup vs baseline: 1.0431x; 1.0195x over previous
//
#include <hip/hip_runtime.h>
#include <hip/hip_bf16.h>

typedef __bf16 bf16x8 __attribute__((ext_vector_type(8)));
typedef float f32x4 __attribute__((ext_vector_type(4)));
typedef int i32x4 __attribute__((ext_vector_type(4)));

#define NB 32
#define NS 200
#define SP 256
#define ND 256
#define NH 6
#define NL 8
#define NBS (NB*NS)      // 6400
#define NZ (NB*NH)       // 192
#define SLAB (SP*ND)     // 65536
#define PSTR 264         // P lds row stride (shorts)

using bf16 = __hip_bfloat16;

enum { EPI_F32 = 0, EPI_RELU_BF = 1 };

__device__ __forceinline__ float b2f(bf16 x) { return __bfloat162float(x); }
__device__ __forceinline__ bf16 f2b(float x) { return __float2bfloat16(x); }
__device__ __forceinline__ unsigned short fbits(float x) { bf16 h = f2b(x); return *(unsigned short*)&h; }

#define MFMA __builtin_amdgcn_mfma_f32_16x16x32_bf16

// async global->LDS, 16B per lane. LDS dest must be wave-uniform base (HW adds lane*16).
__device__ __forceinline__ void gload16(const bf16* g, const short* l) {
    __builtin_amdgcn_global_load_lds(
        (const __attribute__((address_space(1))) unsigned int*)(unsigned long long)(g),
        (__attribute__((address_space(3))) unsigned int*)(unsigned long long)(l), 16, 0, 0);
}

// LDS swizzle: rows are 64B = 4 x 16B units; XOR unit with (row>>1)&3 -> 2-way/bank (free).
// gload_lds dest is linear, so apply the permutation on the per-lane GLOBAL source (m173).
#define GUNIT(lane) ((((lane) & 3) ^ (((lane) >> 3) & 3)) * 8)
#define RUNIT(kcu, fr) ((((kcu) ^ (((fr) >> 1) & 3))) * 8)

// ---------------------------------------------------------------------------
// QKV GEMM (r13-proven best): 64x64 tile, 4 waves (2x2), wave-tile 32x32,
// swizzled LDS. 4 LDS bufs, stage-ahead D=2, ONE barrier/iter.
// Epilogue: Q/K via LDS transpose -> 128B-coalesced stores; V direct (32B segs).
// ---------------------------------------------------------------------------
__global__ __launch_bounds__(256)
void gemm_qkv(const bf16* __restrict__ A, const bf16* __restrict__ Bm,
              const float* __restrict__ qkvb, const float* __restrict__ tnbp,
              bf16* __restrict__ Qb, bf16* __restrict__ Kb, bf16* __restrict__ Vb)
{
    __shared__ __align__(16) char smem[32768];
    short* Asl0 = (short*)smem;                 // [4][64*32]
    short* Bsl0 = (short*)(smem + 16384);       // [4][64*32]
    const int K = 256;
    const int tid  = threadIdx.x;
    const int m0   = blockIdx.y * 64;
    const int n0   = blockIdx.x * 64;
    const int lane = tid & 63, w = tid >> 6;
    const int wm   = (w >> 1) * 32, wn = (w & 1) * 32;
    const int fr   = lane & 15, kcu = lane >> 4;
    const int srow = lane >> 2, schk = GUNIT(lane);

    const bf16* Ag = A  + (long long)m0 * K;
    const bf16* Bg = Bm + (long long)n0 * K;

    f32x4 acc[2][2];
#pragma unroll
    for (int i = 0; i < 2; i++)
#pragma unroll
        for (int j = 0; j < 2; j++) acc[i][j] = (f32x4){0.f,0.f,0.f,0.f};

    auto stage = [&](int buf, int k0) {
        gload16(Ag + (long long)(w*16 + srow)*K + k0 + schk, &Asl0[buf*2048 + (w*16)*32]);
        gload16(Bg + (long long)(w*16 + srow)*K + k0 + schk, &Bsl0[buf*2048 + (w*16)*32]);
    };

    stage(0, 0);
    stage(1, 32);
    for (int t = 0; t < 8; t++) {
        const int buf = t & 3;
        if (t + 2 < 8) {
            stage((t + 2) & 3, (t + 2) * 32);
            asm volatile("s_waitcnt vmcnt(4)" ::: "memory");   // tiles t+1,t+2 in flight; t landed
        } else if (t + 1 < 8) {
            asm volatile("s_waitcnt vmcnt(2)" ::: "memory");
        } else {
            asm volatile("s_waitcnt vmcnt(0)" ::: "memory");
        }
        __builtin_amdgcn_s_barrier();
        __builtin_amdgcn_sched_barrier(0);
        bf16x8 af[2], bfm[2];
#pragma unroll
        for (int i = 0; i < 2; i++) af[i]  = *(const bf16x8*)&Asl0[buf*2048 + (wm + i*16 + fr)*32 + RUNIT(kcu, fr)];
#pragma unroll
        for (int j = 0; j < 2; j++) bfm[j] = *(const bf16x8*)&Bsl0[buf*2048 + (wn + j*16 + fr)*32 + RUNIT(kcu, fr)];
#pragma unroll
        for (int i = 0; i < 2; i++)
#pragma unroll
            for (int j = 0; j < 2; j++)
                acc[i][j] = MFMA(af[i], bfm[j], acc[i][j], 0, 0, 0);
        // no trailing barrier: 4-buf D=2 single-barrier schedule (skew<=1 iter)
    }

    const int xq   = m0 / 1536;          // uniform per block (1536 % 64 == 0)
    const int c1_0 = m0 - xq*1536;
    const int hdq  = c1_0 >> 8;          // 64-dim tile never crosses a head boundary
    const int ddb  = c1_0 & 255;

    if (xq < 2) {
        // ---- LDS-transpose epilogue: T[token][dim], stride 72 shorts
        short* T = (short*)smem;
        __syncthreads();                  // staging bufs dead; reuse
#pragma unroll
        for (int i = 0; i < 2; i++) {
            const int dl0 = wm + i*16 + kcu*4;     // local dim of rg=0
            float bv[4];
#pragma unroll
            for (int rg = 0; rg < 4; rg++) {
                const int cc = c1_0 + dl0 + rg;
                bv[rg] = (cc < 512) ? qkvb[xq*512 + cc] : tnbp[xq*1024 + cc - 512];
            }
#pragma unroll
            for (int j = 0; j < 2; j++) {
                const int tok = wn + j*16 + fr;
                ushort4 pk;
                pk.x = fbits(acc[i][j][0] + bv[0]);
                pk.y = fbits(acc[i][j][1] + bv[1]);
                pk.z = fbits(acc[i][j][2] + bv[2]);
                pk.w = fbits(acc[i][j][3] + bv[3]);
                *(ushort4*)&T[tok*72 + dl0] = pk;
            }
        }
        __syncthreads();
        const int tt = tid >> 2;          // local token
        const int dc = (tid & 3) * 16;    // local dim chunk (32B)
        const int c  = n0 + tt;
        const int bb = c / NS, ss = c - bb*NS;
        bf16* dst = xq ? Kb : Qb;
        bf16* dp  = dst + ((long long)((bb*NH + hdq)*SP + ss))*ND + ddb + dc;
        *(i32x4*)dp       = *(const i32x4*)&T[tt*72 + dc];
        *(i32x4*)(dp + 8) = *(const i32x4*)&T[tt*72 + dc + 8];
    } else {
        // ---- V: Vt[z][d][s], rg spans d -> stride SP; 16 lanes -> 32B segments
#pragma unroll
        for (int i = 0; i < 2; i++) {
            const int dl0 = wm + i*16 + kcu*4;
            float bv[4];
#pragma unroll
            for (int rg = 0; rg < 4; rg++) {
                const int cc = c1_0 + dl0 + rg;
                bv[rg] = (cc < 512) ? qkvb[2*512 + cc] : tnbp[2*1024 + cc - 512];
            }
#pragma unroll
            for (int j = 0; j < 2; j++) {
                const int c = n0 + wn + j*16 + fr;
                const int bb = c / NS, ss = c - bb*NS;
                const long long base = ((long long)((bb*NH + hdq)*ND + ddb + dl0))*SP + ss;
#pragma unroll
                for (int rg = 0; rg < 4; rg++)
                    Vb[base + (long long)rg*SP] = f2b(acc[i][j][rg] + bv[rg]);
            }
        }
    }
}

// ---------------------------------------------------------------------------
// NT GEMM 128x128 for outproj / ff1 / ff2 (r11-proven).
// 3 LDS bufs, D=1, ONE barrier/iter. blockIdx.z = split-K chunk.
// ---------------------------------------------------------------------------
template<int MODE>
__global__ __launch_bounds__(256)
void gemm_nt(const bf16* __restrict__ A, const bf16* __restrict__ Bm,
             int M, int N, int K, int Kspan, long long sOz,
             float* __restrict__ outF, bf16* __restrict__ outBf,
             const float* __restrict__ bias)
{
    __shared__ short Asl[3][128*32];
    __shared__ short Bsl[3][128*32];
    const int tid  = threadIdx.x;
    const int m0   = blockIdx.y * 128;
    const int n0   = blockIdx.x * 128;
    const int kbase= blockIdx.z * Kspan;
    const int lane = tid & 63, w = tid >> 6;
    const int wm   = (w >> 1) * 64, wn = (w & 1) * 64;
    const int fr   = lane & 15, kc = (lane >> 4) * 8;
    const int srow = lane >> 2, schk = (lane & 3) * 8;

    const bf16* Ag = A  + (long long)m0 * K + kbase;
    const bf16* Bg = Bm + (long long)n0 * K + kbase;

    f32x4 acc[4][4];
#pragma unroll
    for (int i = 0; i < 4; i++)
#pragma unroll
        for (int j = 0; j < 4; j++) acc[i][j] = (f32x4){0.f,0.f,0.f,0.f};

    auto stage = [&](int buf, int k0) {
        gload16(Ag + (long long)(w*32      + srow)*K + k0 + schk, &Asl[buf][(w*32     )*32]);
        gload16(Ag + (long long)(w*32 + 16 + srow)*K + k0 + schk, &Asl[buf][(w*32 + 16)*32]);
        gload16(Bg + (long long)(w*32      + srow)*K + k0 + schk, &Bsl[buf][(w*32     )*32]);
        gload16(Bg + (long long)(w*32 + 16 + srow)*K + k0 + schk, &Bsl[buf][(w*32 + 16)*32]);
    };

    const int nt = Kspan >> 5;
    stage(0, 0);
    for (int t = 0; t < nt; t++) {
        const int buf = t % 3;
        if (t + 1 < nt) {
            stage((t + 1) % 3, (t + 1) * 32);
            asm volatile("s_waitcnt vmcnt(4)" ::: "memory");
        } else {
            asm volatile("s_waitcnt vmcnt(0)" ::: "memory");
        }
        __builtin_amdgcn_s_barrier();
        __builtin_amdgcn_sched_barrier(0);
        bf16x8 af[4], bfm[4];
#pragma unroll
        for (int i = 0; i < 4; i++) af[i]  = *(const bf16x8*)&Asl[buf][(wm + i*16 + fr)*32 + kc];
#pragma unroll
        for (int j = 0; j < 4; j++) bfm[j] = *(const bf16x8*)&Bsl[buf][(wn + j*16 + fr)*32 + kc];
#pragma unroll
        for (int i = 0; i < 4; i++)
#pragma unroll
            for (int j = 0; j < 4; j++)
                acc[i][j] = MFMA(af[i], bfm[j], acc[i][j], 0, 0, 0);
    }

    const int rq = (lane >> 4) * 4;
#pragma unroll
    for (int i = 0; i < 4; i++) {
        const int r0 = m0 + wm + i*16 + rq;
#pragma unroll
        for (int j = 0; j < 4; j++) {
            const int c = n0 + wn + j*16 + fr;
            if (MODE == EPI_F32) {
#pragma unroll
                for (int rg = 0; rg < 4; rg++)
                    outF[(long long)blockIdx.z * sOz + (long long)(r0+rg)*N + c] = acc[i][j][rg];
            } else {
                const float bv = bias[c];
#pragma unroll
                for (int rg = 0; rg < 4; rg++)
                    outBf[(long long)(r0+rg)*N + c] = f2b(fmaxf(acc[i][j][rg] + bv, 0.f));
            }
        }
    }
}

// ---------------------------------------------------------------------------
// Fused attention (r11-proven): block = (z, 64-query quarter); grid (192, 4).
// ---------------------------------------------------------------------------
__global__ __launch_bounds__(256)
void attn_fused(const bf16* __restrict__ Qb, const bf16* __restrict__ Kb,
                const bf16* __restrict__ Vtb, const int* __restrict__ tokens,
                bf16* __restrict__ ctx)
{
    __shared__ __align__(16) char smem[2*20480 + 1024 + 1024 + 64*PSTR*2];
    float* red   = (float*)(smem + 40960);
    float* maskv = (float*)(smem + 40960 + 1024);
    short* P     = (short*)(smem + 40960 + 2048);

    const int z  = blockIdx.x;
    const int b  = z / NH, h = z - b*NH;
    const int q0 = blockIdx.y * 64;
    const int tid = threadIdx.x;
    const int lane = tid & 63, w = tid >> 6;
    const int fr = lane & 15, qh = lane >> 4;
    const int kc = qh * 8;
    const int srow = lane >> 2, schk = GUNIT(lane);

    const bf16* Kp = Kb  + (long long)z * SLAB;
    const bf16* Qp = Qb  + (long long)z * SLAB;
    const bf16* Vp = Vtb + (long long)z * SLAB;

    {
        const int s = tid;
        float mv = -1e9f;
        if (s < NS && tokens[b*NS + s] != 0) mv = 0.f;
        maskv[s] = mv;
    }

    auto stage1 = [&](int buf, int k0) {
        short* Ks = (short*)(smem + buf*20480);
        short* Qs = (short*)(smem + buf*20480 + 16384);
#pragma unroll
        for (int r2 = 0; r2 < 4; r2++)
            gload16(Kp + (long long)(w*64 + r2*16 + srow)*ND + k0 + schk, &Ks[(w*64 + r2*16)*32]);
        gload16(Qp + (long long)(q0 + w*16 + srow)*ND + k0 + schk, &Qs[(w*16)*32]);
    };

    f32x4 acc[4][4];
#pragma unroll
    for (int i = 0; i < 4; i++)
#pragma unroll
        for (int j = 0; j < 4; j++) acc[i][j] = (f32x4){0.f,0.f,0.f,0.f};

    stage1(0, 0);
    for (int t = 0; t < 8; t++) {
        const int buf = t & 1;
        if (t + 1 < 8) {
            stage1(buf ^ 1, (t + 1) * 32);
            asm volatile("s_waitcnt vmcnt(5)" ::: "memory");
        } else {
            asm volatile("s_waitcnt vmcnt(0)" ::: "memory");
        }
        __builtin_amdgcn_s_barrier();
        __builtin_amdgcn_sched_barrier(0);
        const short* Ks = (const short*)(smem + buf*20480);
        const short* Qs = (const short*)(smem + buf*20480 + 16384);
        bf16x8 ak[4], bq[4];
#pragma unroll
        for (int i = 0; i < 4; i++) ak[i] = *(const bf16x8*)&Ks[(w*64 + i*16 + fr)*32 + RUNIT(qh, fr)];
#pragma unroll
        for (int j = 0; j < 4; j++) bq[j] = *(const bf16x8*)&Qs[(j*16 + fr)*32 + RUNIT(qh, fr)];
#pragma unroll
        for (int i = 0; i < 4; i++)
#pragma unroll
            for (int j = 0; j < 4; j++)
                acc[i][j] = MFMA(ak[i], bq[j], acc[i][j], 0, 0, 0);
        __builtin_amdgcn_s_barrier();
        __builtin_amdgcn_sched_barrier(0);
    }

    float mk[4][4];
#pragma unroll
    for (int i = 0; i < 4; i++)
#pragma unroll
        for (int rg = 0; rg < 4; rg++) mk[i][rg] = maskv[w*64 + i*16 + qh*4 + rg];
#pragma unroll
    for (int i = 0; i < 4; i++)
#pragma unroll
        for (int j = 0; j < 4; j++)
#pragma unroll
            for (int rg = 0; rg < 4; rg++)
                acc[i][j][rg] = acc[i][j][rg] * 0.0625f + mk[i][rg];

    float pm[4];
#pragma unroll
    for (int j = 0; j < 4; j++) {
        float m = -3.0e38f;
#pragma unroll
        for (int i = 0; i < 4; i++)
#pragma unroll
            for (int rg = 0; rg < 4; rg++) m = fmaxf(m, acc[i][j][rg]);
        m = fmaxf(m, __shfl_xor(m, 16));
        m = fmaxf(m, __shfl_xor(m, 32));
        pm[j] = m;
    }
#pragma unroll
    for (int j = 0; j < 4; j++) red[w*64 + j*16 + fr] = pm[j];
    __syncthreads();
    float gm[4];
#pragma unroll
    for (int j = 0; j < 4; j++)
        gm[j] = fmaxf(fmaxf(red[j*16 + fr], red[64 + j*16 + fr]),
                      fmaxf(red[128 + j*16 + fr], red[192 + j*16 + fr]));
    float ps[4] = {0.f, 0.f, 0.f, 0.f};
#pragma unroll
    for (int i = 0; i < 4; i++)
#pragma unroll
        for (int j = 0; j < 4; j++)
#pragma unroll
            for (int rg = 0; rg < 4; rg++) {
                float e = __expf(acc[i][j][rg] - gm[j]);
                acc[i][j][rg] = e;
                ps[j] += e;
            }
#pragma unroll
    for (int j = 0; j < 4; j++) {
        ps[j] += __shfl_xor(ps[j], 16);
        ps[j] += __shfl_xor(ps[j], 32);
    }
    __syncthreads();
#pragma unroll
    for (int j = 0; j < 4; j++) red[w*64 + j*16 + fr] = ps[j];
    __syncthreads();
    float inv[4];
#pragma unroll
    for (int j = 0; j < 4; j++)
        inv[j] = 1.f / (red[j*16 + fr] + red[64 + j*16 + fr] + red[128 + j*16 + fr] + red[192 + j*16 + fr]);

#pragma unroll
    for (int i = 0; i < 4; i++)
#pragma unroll
        for (int j = 0; j < 4; j++) {
            ushort4 pk;
            pk.x = fbits(acc[i][j][0] * inv[j]);
            pk.y = fbits(acc[i][j][1] * inv[j]);
            pk.z = fbits(acc[i][j][2] * inv[j]);
            pk.w = fbits(acc[i][j][3] * inv[j]);
            *(ushort4*)&P[(j*16 + fr)*PSTR + w*64 + i*16 + qh*4] = pk;
        }
    __syncthreads();

    auto stage2 = [&](int buf, int s0) {
        short* Vs = (short*)(smem + buf*20480);
#pragma unroll
        for (int r2 = 0; r2 < 4; r2++)
            gload16(Vp + (long long)(w*64 + r2*16 + srow)*SP + s0 + schk, &Vs[(w*64 + r2*16)*32]);
    };

    f32x4 acc2[4][4];
#pragma unroll
    for (int i = 0; i < 4; i++)
#pragma unroll
        for (int j = 0; j < 4; j++) acc2[i][j] = (f32x4){0.f,0.f,0.f,0.f};

    stage2(0, 0);
    for (int t = 0; t < 7; t++) {
        const int buf = t & 1;
        if (t + 1 < 7) {
            stage2(buf ^ 1, (t + 1) * 32);
            asm volatile("s_waitcnt vmcnt(4)" ::: "memory");
        } else {
            asm volatile("s_waitcnt vmcnt(0)" ::: "memory");
        }
        __builtin_amdgcn_s_barrier();
        __builtin_amdgcn_sched_barrier(0);
        const short* Vs = (const short*)(smem + buf*20480);
        bf16x8 ap[4], bv[4];
#pragma unroll
        for (int i = 0; i < 4; i++) ap[i] = *(const bf16x8*)&P[(i*16 + fr)*PSTR + t*32 + kc];
#pragma unroll
        for (int j = 0; j < 4; j++) bv[j] = *(const bf16x8*)&Vs[(w*64 + j*16 + fr)*32 + RUNIT(qh, fr)];
#pragma unroll
        for (int i = 0; i < 4; i++)
#pragma unroll
            for (int j = 0; j < 4; j++)
                acc2[i][j] = MFMA(ap[i], bv[j], acc2[i][j], 0, 0, 0);
        __builtin_amdgcn_s_barrier();
        __builtin_amdgcn_sched_barrier(0);
    }

#pragma unroll
    for (int i = 0; i < 4; i++)
#pragma unroll
        for (int j = 0; j < 4; j++)
#pragma unroll
            for (int rg = 0; rg < 4; rg++) {
                const int qg = q0 + i*16 + qh*4 + rg;
                if (qg < NS) {
                    const int d = w*64 + j*16 + fr;
                    ctx[((long long)(b*NS + qg))*1536 + h*256 + d] = f2b(acc2[i][j][rg]);
                }
            }
}

// ---------------------------------------------------------------------------
__global__ void embed_kernel(const int* __restrict__ tokens, const float* __restrict__ tok_emb,
                             const float* __restrict__ pos_emb, float* __restrict__ hf,
                             bf16* __restrict__ hbf)
{
    long long q = (long long)blockIdx.x * 256 + threadIdx.x;   // quad index
    if (q >= (long long)NBS * 64) return;
    long long r = q >> 6;
    int j = (int)(q & 63) * 4;
    int tk = tokens[r];
    int s  = (int)(r % NS);
    float4 tv = *(const float4*)(tok_emb + (long long)tk * ND + j);
    float4 pv = *(const float4*)(pos_emb + s * ND + j);
    float4 v = make_float4(tv.x+pv.x, tv.y+pv.y, tv.z+pv.z, tv.w+pv.w);
    *(float4*)(hf + r*ND + j) = v;
    ushort4 pk;
    pk.x = fbits(v.x); pk.y = fbits(v.y); pk.z = fbits(v.z); pk.w = fbits(v.w);
    *(ushort4*)(hbf + r*ND + j) = pk;
}

// Tiled transpose: out[l][c*outStride + r] = in[l][r*C + c]  (f32 -> bf16)
__global__ __launch_bounds__(256)
void transpose_tile(const float* __restrict__ in, bf16* __restrict__ out,
                    int R, int C, long long inL, long long outL, int outStride)
{
    __shared__ float tl[32][33];
    const int l  = blockIdx.z;
    const int r0 = blockIdx.y * 32, c0 = blockIdx.x * 32;
    const float* ip = in + (long long)l * inL;
    bf16* op = out + (long long)l * outL;
    const int tx = threadIdx.x & 31, ty = threadIdx.x >> 5;
#pragma unroll
    for (int i = 0; i < 4; i++) {
        const int r = r0 + ty + i*8;
        tl[ty + i*8][tx] = ip[(long long)r * C + c0 + tx];
    }
    __syncthreads();
#pragma unroll
    for (int i = 0; i < 4; i++) {
        const int c = c0 + ty + i*8;
        op[(long long)c * outStride + r0 + tx] = f2b(tl[tx][ty + i*8]);
    }
}

__global__ __launch_bounds__(256)
void build_wtns(const float* __restrict__ A1, const float* __restrict__ A2,
                const float* __restrict__ A3, const float* __restrict__ A4,
                bf16* __restrict__ wcat)
{
    int lx = blockIdx.x;
    __shared__ float a1s[32], a2s[128], a3s[128], a4s[32];
    int t = threadIdx.x;
    if (t < 32)  { a1s[t] = A1[lx*32 + t]; a4s[t] = A4[lx*32 + t]; }
    if (t < 128) { a2s[t] = A2[lx*128 + t]; a3s[t] = A3[lx*128 + t]; }
    __syncthreads();
    int d = t;
    int p = d >> 6, q = (d >> 4) & 3, rr = (d >> 2) & 3, tt = d & 3;
    for (int i = 0; i < 4; i++) {
        float w1_0 = a1s[(p*2 + 0)*4 + i];
        float w1_1 = a1s[(p*2 + 1)*4 + i];
        for (int j = 0; j < 8; j++) {
            float c1_0 = w1_0 * a2s[((q*2+0)*2+0)*8 + j] + w1_1 * a2s[((q*2+1)*2+0)*8 + j];
            float c1_1 = w1_0 * a2s[((q*2+0)*2+1)*8 + j] + w1_1 * a2s[((q*2+1)*2+1)*8 + j];
            for (int kk = 0; kk < 8; kk++) {
                float c2_0 = c1_0 * a3s[((rr*2+0)*2+0)*8 + kk] + c1_1 * a3s[((rr*2+1)*2+0)*8 + kk];
                float c2_1 = c1_0 * a3s[((rr*2+0)*2+1)*8 + kk] + c1_1 * a3s[((rr*2+1)*2+1)*8 + kk];
                for (int ll = 0; ll < 4; ll++) {
                    float sv = c2_0 * a4s[(tt*2 + 0)*4 + ll] + c2_1 * a4s[(tt*2 + 1)*4 + ll];
                    int e = ((i*8 + j)*8 + kk)*4 + ll;
                    wcat[((long long)lx * 1536 + 512 + e) * 256 + d] = f2b(sv);
                }
            }
        }
    }
}

// out = LN(resid + raw0 + raw1 + bias) * g + b  (float4 vectorized)
__global__ __launch_bounds__(256)
void ln_kernel(const float* __restrict__ raw0, const float* __restrict__ raw1,
               const float* __restrict__ bias, const float* __restrict__ resid,
               const float* __restrict__ g, const float* __restrict__ bb,
               float* __restrict__ outF, bf16* __restrict__ outBf)
{
    int w = threadIdx.x >> 6, lane = threadIdx.x & 63;
    long long r = (long long)blockIdx.x * 4 + w;
    long long base = r * ND + lane * 4;
    float4 x  = *(const float4*)(resid + base);
    float4 y0 = *(const float4*)(raw0 + base);
    float4 y1 = *(const float4*)(raw1 + base);
    float4 bs = *(const float4*)(bias + lane * 4);
    x.x += y0.x + y1.x + bs.x;
    x.y += y0.y + y1.y + bs.y;
    x.z += y0.z + y1.z + bs.z;
    x.w += y0.w + y1.w + bs.w;
    float s = x.x + x.y + x.z + x.w;
#pragma unroll
    for (int o = 32; o; o >>= 1) s += __shfl_xor(s, o);
    float mean = s * (1.f/256.f);
    float vs = (x.x-mean)*(x.x-mean) + (x.y-mean)*(x.y-mean)
             + (x.z-mean)*(x.z-mean) + (x.w-mean)*(x.w-mean);
#pragma unroll
    for (int o = 32; o; o >>= 1) vs += __shfl_xor(vs, o);
    float rs = rsqrtf(vs * (1.f/256.f) + 1e-6f);
    float4 gv = *(const float4*)(g  + lane * 4);
    float4 bv = *(const float4*)(bb + lane * 4);
    float4 o4;
    o4.x = (x.x - mean) * rs * gv.x + bv.x;
    o4.y = (x.y - mean) * rs * gv.y + bv.y;
    o4.z = (x.z - mean) * rs * gv.z + bv.z;
    o4.w = (x.w - mean) * rs * gv.w + bv.w;
    *(float4*)(outF + base) = o4;
    ushort4 pk;
    pk.x = fbits(o4.x); pk.y = fbits(o4.y); pk.z = fbits(o4.z); pk.w = fbits(o4.w);
    *(ushort4*)(outBf + base) = pk;
}

// ---------------------------------------------------------------------------
extern "C" void kernel_launch(void* const* d_in, const int* in_sizes, int n_in,
                              void* d_out, int out_size, void* d_ws, size_t ws_size,
                              hipStream_t stream)
{
    const int*   tokens  = (const int*)  d_in[0];
    const float* tok_emb = (const float*)d_in[1];
    const float* pos_emb = (const float*)d_in[2];
    const float* wqkv_w  = (const float*)d_in[3];
    const float* wqkv_b  = (const float*)d_in[4];
    const float* A1      = (const float*)d_in[5];
    const float* A2      = (const float*)d_in[6];
    const float* A3      = (const float*)d_in[7];
    const float* A4      = (const float*)d_in[8];
    const float* tnb     = (const float*)d_in[9];
    const float* out_w   = (const float*)d_in[10];
    const float* out_b   = (const float*)d_in[11];
    const float* ff1_w   = (const float*)d_in[12];
    const float* ff1_b   = (const float*)d_in[13];
    const float* ff2_w   = (const float*)d_in[14];
    const float* ff2_b   = (const float*)d_in[15];
    const float* ln1_g   = (const float*)d_in[16];
    const float* ln1_b   = (const float*)d_in[17];
    const float* ln2_g   = (const float*)d_in[18];
    const float* ln2_b   = (const float*)d_in[19];

    char* ws = (char*)d_ws;
    size_t off = 0;
    auto alloc = [&](size_t bytes) -> char* {
        char* p = ws + off;
        off += (bytes + 255) & ~(size_t)255;
        return p;
    };
    float* hf    = (float*)alloc((size_t)NBS * ND * 4);
    bf16*  hbf   = (bf16*) alloc((size_t)NBS * ND * 2);
    bf16*  wcat  = (bf16*) alloc(24ull * 1536 * 256 * 2);
    bf16*  owt   = (bf16*) alloc(8ull * 256 * 1536 * 2);
    bf16*  f1wt  = (bf16*) alloc(8ull * 1024 * 256 * 2);
    bf16*  f2wt  = (bf16*) alloc(8ull * 256 * 1024 * 2);
    bf16*  Qb    = (bf16*) alloc((size_t)NZ * SLAB * 2);
    bf16*  Kb    = (bf16*) alloc((size_t)NZ * SLAB * 2);
    bf16*  Vtb   = (bf16*) alloc((size_t)NZ * SLAB * 2);
    bf16*  ctxg  = (bf16*) alloc((size_t)NBS * 1536 * 2);
    bf16*  ffn   = (bf16*) alloc((size_t)NBS * 1024 * 2);
    float* raw   = (float*)alloc((size_t)NBS * ND * 4 * 2);   // 2 split-K partials
    float* out1f = (float*)alloc((size_t)NBS * ND * 4);
    bf16*  out1bf= (bf16*) alloc((size_t)NBS * ND * 2);
    if (off > ws_size) return;
    float* raw1 = raw + (size_t)NBS * ND;

    // No memset of Q/K/Vt pads. Pad content (poison) is inert: K-pads are
    // masked (-1e9 -> exp underflows to exactly 0), P[s>=200]==0 multiplies
    // Vt-pad garbage to 0, and pad-q outputs are never stored (qg<NS guard).

    embed_kernel<<<1600, 256, 0, stream>>>(tokens, tok_emb, pos_emb, hf, hbf);
    transpose_tile<<<dim3(16, 8, 24), 256, 0, stream>>>(
        wqkv_w, wcat, 256, 512, 256ll*512, 1536ll*256, 256);
    build_wtns<<<24, 256, 0, stream>>>(A1, A2, A3, A4, wcat);
    transpose_tile<<<dim3(8, 48, 8), 256, 0, stream>>>(
        out_w, owt, 1536, 256, 1536ll*256, 256ll*1536, 1536);
    transpose_tile<<<dim3(32, 8, 8), 256, 0, stream>>>(
        ff1_w, f1wt, 256, 1024, 256ll*1024, 1024ll*256, 256);
    transpose_tile<<<dim3(8, 32, 8), 256, 0, stream>>>(
        ff2_w, f2wt, 1024, 256, 1024ll*256, 256ll*1024, 1024);

    for (int l = 0; l < NL; l++) {
        const bf16* wl = wcat + (long long)l * 3 * 1536 * 256;
        // merged QKV: A = qkv weights [4608,256], B = activations [6400,256]
        gemm_qkv<<<dim3(100, 72, 1), 256, 0, stream>>>(
            wl, hbf, wqkv_b + l * 3 * 512, tnb + l * 3 * 1024, Qb, Kb, Vtb);
        // fused attention -> ctxg [6400][1536]
        attn_fused<<<dim3(NZ, 4), 256, 0, stream>>>(Qb, Kb, Vtb, tokens, ctxg);
        // out projection, split-K=2 partials (no atomics)
        gemm_nt<EPI_F32><<<dim3(2, 50, 2), 256, 0, stream>>>(
            ctxg, owt + (long long)l * 256 * 1536, NBS, 256, 1536, 768, (long long)NBS*ND,
            raw, nullptr, nullptr);
        ln_kernel<<<1600, 256, 0, stream>>>(raw, raw1, out_b + l * 256, hf,
                                            ln1_g + l * 256, ln1_b + l * 256, out1f, out1bf);
        // FFN
        gemm_nt<EPI_RELU_BF><<<dim3(8, 50, 1), 256, 0, stream>>>(
            out1bf, f1wt + (long long)l * 1024 * 256, NBS, 1024, 256, 256, 0,
            nullptr, ffn, ff1_b + l * 1024);
        gemm_nt<EPI_F32><<<dim3(2, 50, 2), 256, 0, stream>>>(
            ffn, f2wt + (long long)l * 256 * 1024, NBS, 256, 1024, 512, (long long)NBS*ND,
            raw, nullptr, nullptr);
        ln_kernel<<<1600, 256, 0, stream>>>(raw, raw1, ff2_b + l * 256, out1f,
                                            ln2_g + l * 256, ln2_b + l * 256,
                                            (l == NL - 1) ? (float*)d_out : hf, hbf);
    }
}